// Round 20
// baseline (143.295 us; speedup 1.0000x reference)
//
#include <hip/hip_runtime.h>
#include <math.h>

#define B_  64
#define L_  2048
#define DM  12
#define DI  24
#define DS  16
#define DC  4
#define DTR 1
#define T_  (B_ * L_)        // 131072 tokens
#define NCHUNK 128
#define CHUNK  16            // L_ / NCHUNK

// ---------------- ws layout (floats) — total 18,679,808 (74.7 MB, proven) ----
// xi  : T*DI   3,145,728
// zs  : T*DI   3,145,728
// y   : T*DI   3,145,728
// dt  : T_       131,072
// Bm  : T*DS   2,097,152
// Cm  : T*DS   2,097,152
// Sd  : B*DI*NCHUNK          196,608
// H   : B*DI*NCHUNK*DS     3,145,728   (scan2 overwrites with H0 IN PLACE)
// xf  : B*DM*L             1,572,864
// part: 2048 (512 used)

__device__ __forceinline__ float siluf(float v)  { return v / (1.0f + __expf(-v)); }
__device__ __forceinline__ float eluf(float v) { return v > 0.0f ? v : __expf(v) - 1.0f; }

// Branch-free erf (Abramowitz-Stegun 7.1.26, |err| <= 1.5e-7) + gelu
__device__ __forceinline__ float fast_erff(float x) {
    const float ax = fabsf(x);
    const float t  = 1.0f / fmaf(0.3275911f, ax, 1.0f);
    float p = fmaf(1.061405429f, t, -1.453152027f);
    p = fmaf(p, t, 1.421413741f);
    p = fmaf(p, t, -0.284496736f);
    p = fmaf(p, t, 0.254829592f);
    p *= t;
    const float r = 1.0f - p * __expf(-ax * ax);
    return copysignf(r, x);
}
__device__ __forceinline__ float geluf(float v) {
    return 0.5f * v * (1.0f + fast_erff(v * 0.70710678118654752440f));
}

// DPP sums: quad_perm{1,0,3,2}=0xB1 adds lane^1; quad_perm{2,3,0,1}=0x4E adds lane^2
// (chain validated on-HW rounds 3/4/6/7/19: absmax 0.0)
#define DPP_ADD(p, ctrl) \
    (p) += __int_as_float(__builtin_amdgcn_update_dpp(0, __float_as_int(p), (ctrl), 0xF, 0xF, true))

// ============ K_A: merged k_proj (blocks 0..511) + k_fft (blocks 512..895) ============
__global__ __launch_bounds__(256) void k_proj_fft(
    const float* __restrict__ x, const float* __restrict__ w_in,
    const float* __restrict__ conv_w, const float* __restrict__ conv_b,
    const float* __restrict__ xproj_w,
    float* __restrict__ xi_out, float* __restrict__ zs_out,
    float* __restrict__ dt_out, float* __restrict__ Bm_out,
    float* __restrict__ Cm_out, float* __restrict__ xfT)
{
    __shared__ float smem[12620];
    const int tid = threadIdx.x;

    if (blockIdx.x < 512) {
        // ---------------- proj body ----------------
        float* s_st = smem + 6476;
        const int b   = blockIdx.x >> 3;
        const int l0  = (blockIdx.x & 7) << 8;
        const int l   = l0 + tid;
        const int t   = b * L_ + l;
        const size_t t0 = (size_t)b * L_ + l0;

        float xv[DM];
        *(float4*)&xv[0] = *(const float4*)&x[t * DM + 0];
        *(float4*)&xv[4] = *(const float4*)&x[t * DM + 4];
        *(float4*)&xv[8] = *(const float4*)&x[t * DM + 8];

        float zsv[DI];
#pragma unroll
        for (int e = 0; e < DI; ++e) {
            float acc = 0.0f, accz = 0.0f;
#pragma unroll
            for (int d = 0; d < DM; ++d) {
                acc  += xv[d] * w_in[e * DM + d];
                accz += xv[d] * w_in[(DI + e) * DM + d];
            }
            smem[(tid + 3) * 25 + e] = acc;
            zsv[e] = siluf(accz);
        }
        if (tid < 3) {
            const int lh = l0 - 3 + tid;
            if (lh < 0) {
                for (int e = 0; e < DI; ++e) smem[tid * 25 + e] = 0.0f;
            } else {
                const int th = b * L_ + lh;
                float xh[DM];
                for (int d = 0; d < DM; ++d) xh[d] = x[th * DM + d];
                for (int e = 0; e < DI; ++e) {
                    float acc = 0.0f;
                    for (int d = 0; d < DM; ++d) acc += xh[d] * w_in[e * DM + d];
                    smem[tid * 25 + e] = acc;
                }
            }
        }
#pragma unroll
        for (int e = 0; e < DI; ++e) s_st[tid * DI + e] = zsv[e];
        __syncthreads();
        {
            float4* g = (float4*)(zs_out + t0 * DI);
            const float4* s4 = (const float4*)s_st;
#pragma unroll
            for (int k = 0; k < 6; ++k) g[k * 256 + tid] = s4[k * 256 + tid];
        }

        float xi[DI];
#pragma unroll
        for (int dch = 0; dch < DI; ++dch) {
            float acc = conv_b[dch];
#pragma unroll
            for (int k = 0; k < DC; ++k)
                acc += smem[(tid + k) * 25 + dch] * conv_w[dch * DC + k];
            xi[dch] = siluf(acc);
        }
        float dt = 0.0f;
#pragma unroll
        for (int d = 0; d < DI; ++d) dt += xi[d] * xproj_w[d];
        dt_out[t] = dt;
        float Bv[DS], Cv[DS];
#pragma unroll
        for (int e = 0; e < DS; ++e) {
            float accB = 0.0f, accC = 0.0f;
#pragma unroll
            for (int d = 0; d < DI; ++d) {
                accB += xi[d] * xproj_w[(1 + e) * DI + d];
                accC += xi[d] * xproj_w[(1 + DS + e) * DI + d];
            }
            Bv[e] = accB;
            Cv[e] = accC;
        }

        __syncthreads();
#pragma unroll
        for (int e = 0; e < DI; ++e) s_st[tid * DI + e] = xi[e];
        __syncthreads();
        {
            float4* g = (float4*)(xi_out + t0 * DI);
            const float4* s4 = (const float4*)s_st;
#pragma unroll
            for (int k = 0; k < 6; ++k) g[k * 256 + tid] = s4[k * 256 + tid];
        }
        __syncthreads();
#pragma unroll
        for (int e = 0; e < DS; ++e) s_st[tid * DS + e] = Bv[e];
        __syncthreads();
        {
            float4* g = (float4*)(Bm_out + t0 * DS);
            const float4* s4 = (const float4*)s_st;
#pragma unroll
            for (int k = 0; k < 4; ++k) g[k * 256 + tid] = s4[k * 256 + tid];
        }
        __syncthreads();
#pragma unroll
        for (int e = 0; e < DS; ++e) s_st[tid * DS + e] = Cv[e];
        __syncthreads();
        {
            float4* g = (float4*)(Cm_out + t0 * DS);
            const float4* s4 = (const float4*)s_st;
#pragma unroll
            for (int k = 0; k < 4; ++k) g[k * 256 + tid] = s4[k * 256 + tid];
        }
    } else {
        // ---------------- fft body ----------------
        float* re  = smem;
        float* im  = smem + 2048;
        float* twr = smem + 4096;
        float* twi = smem + 5120;
        const int bid = blockIdx.x - 512;
        const int b   = bid / (DM / 2);
        const int p   = bid % (DM / 2);
        for (int j = tid; j < 1024; j += 256) {
            const float ang = -6.283185307179586f * (float)j * (1.0f / 2048.0f);
            float s, c;
            sincosf(ang, &s, &c);
            twr[j] = c; twi[j] = s;
        }
        for (int i = tid; i < 2048; i += 256) {
            const int r = (int)(__brev((unsigned)i) >> 21);
            const float2 v = *(const float2*)&x[(size_t)(b * L_ + i) * DM + 2 * p];
            re[r] = v.x;
            im[r] = v.y;
        }
        __syncthreads();
        for (int s = 1; s <= 11; ++s) {
            const int half  = 1 << (s - 1);
            const int tstep = 2048 >> s;
            for (int i = tid; i < 1024; i += 256) {
                const int j   = i & (half - 1);
                const int grp = i >> (s - 1);
                const int pos = (grp << s) + j;
                const float wr = twr[j * tstep], wi = twi[j * tstep];
                const float ar = re[pos + half], ai = im[pos + half];
                const float vr = wr * ar - wi * ai;
                const float vi = wr * ai + wi * ar;
                const float ur = re[pos], ui = im[pos];
                re[pos] = ur + vr;          im[pos] = ui + vi;
                re[pos + half] = ur - vr;   im[pos + half] = ui - vi;
            }
            __syncthreads();
        }
        float* row1 = xfT + (size_t)(b * DM + 2 * p) * L_;
        float* row2 = row1 + L_;
        for (int k = tid; k < 2048; k += 256) {
            const int nk = (2048 - k) & 2047;
            const float zr = re[k],  zi = im[k];
            const float qr = re[nk], qi = im[nk];
            const float e1r = zr + qr, e1i = zi - qi;
            const float e2r = zr - qr, e2i = zi + qi;
            row1[k] = 0.5f * sqrtf(e1r * e1r + e1i * e1i);
            row2[k] = 0.5f * sqrtf(e2r * e2r + e2i * e2i);
        }
    }
}

// ============ S1: chunk scan — lane quad (d, q∈0..3) owns 4 n-states each ============
// block = 384 = 4 chunks x 24 d x 4 q; grid = B*(NCHUNK/4) = 2048 blocks = 12288 waves
__global__ __launch_bounds__(384) void k_scan1(
    const float* __restrict__ dt_in, const float* __restrict__ xi,
    const float* __restrict__ Bm, const float* __restrict__ A_log,
    const float* __restrict__ dt_w, const float* __restrict__ dt_b,
    float* __restrict__ Sd, float* __restrict__ H)
{
    const int tid = threadIdx.x;
    const int q   = tid & 3;
    const int d   = (tid >> 2) % DI;
    const int cl  = tid / (4 * DI);       // 0..3
    const int b   = blockIdx.x >> 5;
    const int c   = ((blockIdx.x & 31) << 2) + cl;
    const int t0  = b * L_ + c * CHUNK;

    float An[4];
#pragma unroll
    for (int j = 0; j < 4; ++j) An[j] = -__expf(A_log[d * DS + q * 4 + j]);
    const float dtw = dt_w[d], dtb = dt_b[d];

    float h[4] = {0.0f, 0.0f, 0.0f, 0.0f};
    float sumdel = 0.0f;

    const float*  pDt = dt_in + t0;
    const float*  pX  = xi + (size_t)t0 * DI + d;
    const float4* pB  = (const float4*)(Bm + (size_t)t0 * DS);

#pragma unroll 4
    for (int i = 0; i < CHUNK; ++i) {
        const float v = fmaf(pDt[i], dtw, dtb);
        const float e = __expf(v);
        const float delta = (v > 20.0f) ? v : __logf(1.0f + e);
        const float u = delta * pX[i * DI];
        sumdel += delta;
        const float4 Bq = pB[i * 4 + q];
#pragma unroll
        for (int j = 0; j < 4; ++j) {
            const float a = __expf(delta * An[j]);
            h[j] = a * h[j] + u * (&Bq.x)[j];
        }
    }
    const int cu = (b * DI + d) * NCHUNK + c;
    if (q == 0) Sd[cu] = sumdel;
    float4* pH = (float4*)(H + (size_t)cu * DS + q * 4);
    pH[0] = make_float4(h[0], h[1], h[2], h[3]);
}

// ============ S2: combine IN PLACE (H <- H0); unchanged ============
__global__ __launch_bounds__(256) void k_scan2(
    const float* __restrict__ Sd, float* __restrict__ H,
    const float* __restrict__ A_log)
{
    const int idx  = blockIdx.x * 256 + threadIdx.x;  // 24576 = (b*DI+d)*16 + n
    const int n    = idx & 15;
    const int rest = idx >> 4;                        // b*DI + d
    const int d    = rest % DI;
    const float An = -__expf(A_log[d * DS + n]);
    float Hc = 0.0f;
    const int base = rest * NCHUNK;
    for (int cg = 0; cg < NCHUNK / 8; ++cg) {
        float sd[8], hh[8];
#pragma unroll
        for (int k = 0; k < 8; ++k) {
            sd[k] = Sd[base + cg * 8 + k];
            hh[k] = H[(base + cg * 8 + k) * DS + n];
        }
        float aa[8];
#pragma unroll
        for (int k = 0; k < 8; ++k) aa[k] = __expf(An * sd[k]);
#pragma unroll
        for (int k = 0; k < 8; ++k) {
            H[(base + cg * 8 + k) * DS + n] = Hc;   // in-place: H becomes H0
            Hc = aa[k] * Hc + hh[k];
        }
    }
}

// ============ S3: replay + gate — 4 n-states/lane, quad DPP sum for the C-dot ============
__global__ __launch_bounds__(384) void k_scan3(
    const float* __restrict__ dt_in, const float* __restrict__ xi,
    const float* __restrict__ Bm, const float* __restrict__ Cm,
    const float* __restrict__ zs, const float* __restrict__ Dp,
    const float* __restrict__ H0, const float* __restrict__ A_log,
    const float* __restrict__ dt_w, const float* __restrict__ dt_b,
    float* __restrict__ y_out)
{
    const int tid = threadIdx.x;
    const int q   = tid & 3;
    const int d   = (tid >> 2) % DI;
    const int cl  = tid / (4 * DI);       // 0..3
    const int b   = blockIdx.x >> 5;
    const int c   = ((blockIdx.x & 31) << 2) + cl;
    const int t0  = b * L_ + c * CHUNK;

    float An[4];
#pragma unroll
    for (int j = 0; j < 4; ++j) An[j] = -__expf(A_log[d * DS + q * 4 + j]);
    const float dtw = dt_w[d], dtb = dt_b[d];
    const float Dpd = Dp[d];

    const int cu = (b * DI + d) * NCHUNK + c;
    float h[4];
    {
        const float4 a0 = *(const float4*)(H0 + (size_t)cu * DS + q * 4);
        h[0] = a0.x; h[1] = a0.y; h[2] = a0.z; h[3] = a0.w;
    }

    const float*  pDt = dt_in + t0;
    const float*  pX  = xi + (size_t)t0 * DI + d;
    const float*  pZ  = zs + (size_t)t0 * DI + d;
    const float4* pB  = (const float4*)(Bm + (size_t)t0 * DS);
    const float4* pC  = (const float4*)(Cm + (size_t)t0 * DS);
    float*        pY  = y_out + (size_t)t0 * DI + d;

#pragma unroll 4
    for (int i = 0; i < CHUNK; ++i) {
        const float v = fmaf(pDt[i], dtw, dtb);
        const float e = __expf(v);
        const float delta = (v > 20.0f) ? v : __logf(1.0f + e);
        const float xiv = pX[i * DI];
        const float u = delta * xiv;
        const float4 Bq = pB[i * 4 + q];
        const float4 Cq = pC[i * 4 + q];
        float p = 0.0f;
#pragma unroll
        for (int j = 0; j < 4; ++j) {
            const float a = __expf(delta * An[j]);
            h[j] = a * h[j] + u * (&Bq.x)[j];
            p += h[j] * (&Cq.x)[j];
        }
        DPP_ADD(p, 0xB1);    // + lane^1
        DPP_ADD(p, 0x4E);    // + lane^2 -> full 16-state sum across the quad
        if (q == 0) pY[i * DI] = (p + xiv * Dpd) * pZ[i * DI];
    }
}

// ============ K_C: tail v6 — thread-per-token, front-loaded (unchanged) ============
__global__ __launch_bounds__(256, 2) void k_tail(
    const float* __restrict__ yg, const float* __restrict__ xfT,
    const float* __restrict__ out_w,
    const float* __restrict__ ln1_g, const float* __restrict__ ln1_b,
    const float* __restrict__ w1, const float* __restrict__ b1,
    const float* __restrict__ w2, const float* __restrict__ b2,
    const float* __restrict__ lng, const float* __restrict__ lnb,
    const float* __restrict__ cnn_w, const float* __restrict__ cnn_b,
    const float* __restrict__ l1w, const float* __restrict__ l1b,
    const float* __restrict__ l2w, const float* __restrict__ l2b,
    const float* __restrict__ l3w,
    float* __restrict__ part)
{
    __shared__ float sV[DM];
    __shared__ float sC0;
    __shared__ float sred[256];

    const int tid = threadIdx.x;
    const int b   = blockIdx.x >> 3;
    const int l   = ((blockIdx.x & 7) << 8) + tid;
    const int t   = b * L_ + l;

    float y[DI];
#pragma unroll
    for (int e = 0; e < DI; ++e) y[e] = yg[(size_t)t * DI + e];
    float xfm[DM], xf0[DM], xfp[DM];
#pragma unroll
    for (int i = 0; i < DM; ++i) {
        const float* row = xfT + (size_t)(b * DM + i) * L_;
        xfm[i] = (l == 0)      ? 0.0f : row[l - 1];
        xf0[i] = row[l];
        xfp[i] = (l == L_ - 1) ? 0.0f : row[l + 1];
    }

    if (tid < DM) {
        float acc = 0.0f;
#pragma unroll
        for (int e = 0; e < 20; ++e) acc += l3w[e] * l2w[e * DM + tid];
        sV[tid] = acc;
    }
    if (tid == DM) {
        float c = 0.0f;
#pragma unroll
        for (int e = 0; e < 20; ++e) c += l2b[e] * l3w[e];
        sC0 = c;
    }
    __syncthreads();

    float m[DM];
#pragma unroll
    for (int j = 0; j < DM; ++j) {
        float acc = 0.0f;
#pragma unroll
        for (int e = 0; e < DI; ++e) acc += y[e] * out_w[j * DI + e];
        m[j] = acc;
    }
    float mean = 0.0f;
#pragma unroll
    for (int j = 0; j < DM; ++j) mean += m[j];
    mean *= (1.0f / DM);
    float var = 0.0f;
#pragma unroll
    for (int j = 0; j < DM; ++j) { const float dv = m[j] - mean; var += dv * dv; }
    var *= (1.0f / DM);
    const float inv1 = rsqrtf(var + 1e-12f);
    float h[DM];
#pragma unroll
    for (int j = 0; j < DM; ++j) h[j] = (m[j] - mean) * inv1 * ln1_g[j] + ln1_b[j];

    float ff[4 * DM];
#pragma unroll
    for (int e = 0; e < 4 * DM; ++e) {
        float acc = b1[e];
#pragma unroll
        for (int j = 0; j < DM; ++j) acc += h[j] * w1[e * DM + j];
        ff[e] = geluf(acc);
    }
    float f2[DM];
#pragma unroll
    for (int j = 0; j < DM; ++j) {
        float acc = b2[j];
#pragma unroll
        for (int e = 0; e < 4 * DM; ++e) acc += ff[e] * w2[j * (4 * DM) + e];
        f2[j] = acc + h[j];
    }
    mean = 0.0f;
#pragma unroll
    for (int j = 0; j < DM; ++j) mean += f2[j];
    mean *= (1.0f / DM);
    var = 0.0f;
#pragma unroll
    for (int j = 0; j < DM; ++j) { const float dv = f2[j] - mean; var += dv * dv; }
    var *= (1.0f / DM);
    const float inv2 = rsqrtf(var + 1e-12f);
    float xm[DM];
#pragma unroll
    for (int j = 0; j < DM; ++j) xm[j] = (f2[j] - mean) * inv2 * lng[j] + lnb[j];

    float xc[DM];
#pragma unroll
    for (int o = 0; o < DM; ++o) {
        float acc = cnn_b[o];
#pragma unroll
        for (int i = 0; i < DM; ++i) {
            const int wb = (o * DM + i) * 3;
            acc += xfm[i] * cnn_w[wb] + xf0[i] * cnn_w[wb + 1] + xfp[i] * cnn_w[wb + 2];
        }
        xc[o] = acc;
    }

    float o3 = sC0;
#pragma unroll
    for (int d = 0; d < DM; ++d) {
        float acc = l1b[d];
#pragma unroll
        for (int e = 0; e < DM; ++e) acc += xm[e] * l1w[d * (2 * DM) + e];
#pragma unroll
        for (int e = 0; e < DM; ++e) acc += xc[e] * l1w[d * (2 * DM) + DM + e];
        o3 += eluf(acc) * sV[d];
    }

    sred[tid] = o3;
    __syncthreads();
    for (int s = 128; s > 0; s >>= 1) {
        if (tid < s) sred[tid] += sred[tid + s];
        __syncthreads();
    }
    if (tid == 0) part[blockIdx.x] = sred[0];
}

// ============ K_D: final per-batch mean + l3b + sigmoid ============
__global__ void k_final(const float* __restrict__ part, const float* __restrict__ l3b,
                        float* __restrict__ out)
{
    const int b = threadIdx.x;
    if (b < B_) {
        float s = 0.0f;
        for (int i = 0; i < 8; ++i) s += part[b * 8 + i];
        s = s * (1.0f / (float)L_) + l3b[0];
        out[b] = 1.0f / (1.0f + __expf(-s));
    }
}

extern "C" void kernel_launch(void* const* d_in, const int* in_sizes, int n_in,
                              void* d_out, int out_size, void* d_ws, size_t ws_size,
                              hipStream_t stream)
{
    const float* x        = (const float*)d_in[0];
    const float* in_w     = (const float*)d_in[1];
    const float* conv_w   = (const float*)d_in[2];
    const float* conv_b   = (const float*)d_in[3];
    const float* xproj_w  = (const float*)d_in[4];
    const float* dt_w     = (const float*)d_in[5];
    const float* dt_b     = (const float*)d_in[6];
    const float* A_log    = (const float*)d_in[7];
    const float* Dp       = (const float*)d_in[8];
    const float* out_w    = (const float*)d_in[9];
    const float* ln1_g    = (const float*)d_in[10];
    const float* ln1_b    = (const float*)d_in[11];
    const float* ffn_w1   = (const float*)d_in[12];
    const float* ffn_b1   = (const float*)d_in[13];
    const float* ffn_w2   = (const float*)d_in[14];
    const float* ffn_b2   = (const float*)d_in[15];
    const float* ffn_ln_g = (const float*)d_in[16];
    const float* ffn_ln_b = (const float*)d_in[17];
    const float* cnn_w    = (const float*)d_in[18];
    const float* cnn_b    = (const float*)d_in[19];
    const float* l1w      = (const float*)d_in[20];
    const float* l1b      = (const float*)d_in[21];
    const float* l2w      = (const float*)d_in[22];
    const float* l2b      = (const float*)d_in[23];
    const float* l3w      = (const float*)d_in[24];
    const float* l3b      = (const float*)d_in[25];
    float* out = (float*)d_out;

    float* ws = (float*)d_ws;
    const size_t nTDI = (size_t)T_ * DI;
    const size_t nTDS = (size_t)T_ * DS;
    const size_t nCH  = (size_t)B_ * DI * NCHUNK;        // 196,608
    float* w_xi   = ws;
    float* w_zs   = w_xi + nTDI;
    float* w_y    = w_zs + nTDI;
    float* w_dt   = w_y + nTDI;
    float* w_Bm   = w_dt + T_;
    float* w_Cm   = w_Bm + nTDS;
    float* w_Sd   = w_Cm + nTDS;
    float* w_H    = w_Sd + nCH;
    float* w_xf   = w_H + nCH * DS;
    float* w_part = w_xf + (size_t)B_ * DM * L_;

    k_proj_fft<<<512 + B_ * (DM / 2), 256, 0, stream>>>(
        x, in_w, conv_w, conv_b, xproj_w,
        w_xi, w_zs, w_dt, w_Bm, w_Cm, w_xf);
    k_scan1<<<B_ * (NCHUNK / 4), 384, 0, stream>>>(w_dt, w_xi, w_Bm, A_log,
                                                   dt_w, dt_b, w_Sd, w_H);
    k_scan2<<<96, 256, 0, stream>>>(w_Sd, w_H, A_log);
    k_scan3<<<B_ * (NCHUNK / 4), 384, 0, stream>>>(w_dt, w_xi, w_Bm, w_Cm, w_zs, Dp,
                                                   w_H, A_log, dt_w, dt_b, w_y);
    k_tail<<<512, 256, 0, stream>>>(w_y, w_xf, out_w,
                                    ln1_g, ln1_b, ffn_w1, ffn_b1, ffn_w2, ffn_b2,
                                    ffn_ln_g, ffn_ln_b, cnn_w, cnn_b,
                                    l1w, l1b, l2w, l2b, l3w, w_part);
    k_final<<<1, 64, 0, stream>>>(w_part, l3b, out);
}

// Round 21
// 143.118 us; speedup vs baseline: 1.0012x; 1.0012x over previous
//
#include <hip/hip_runtime.h>
#include <math.h>

#define B_  64
#define L_  2048
#define DM  12
#define DI  24
#define DS  16
#define DC  4
#define DTR 1
#define T_  (B_ * L_)        // 131072 tokens
#define NCHUNK 128
#define CHUNK  16            // L_ / NCHUNK

// ---------------- ws layout (floats) — total 18,679,808 (74.7 MB, proven) ----
// xi  : T*DI   3,145,728
// zs  : T*DI   3,145,728
// y   : T*DI   3,145,728
// dt  : T_       131,072
// Bm  : T*DS   2,097,152
// Cm  : T*DS   2,097,152
// Sd  : B*DI*NCHUNK          196,608
// H   : B*DI*NCHUNK*DS     3,145,728   (scan2 overwrites with H0 IN PLACE)
// xf  : B*DM*L             1,572,864
// part: 2048 (512 used)

__device__ __forceinline__ float siluf(float v)  { return v / (1.0f + __expf(-v)); }
__device__ __forceinline__ float eluf(float v) { return v > 0.0f ? v : __expf(v) - 1.0f; }

// Branch-free erf (Abramowitz-Stegun 7.1.26, |err| <= 1.5e-7) + gelu
__device__ __forceinline__ float fast_erff(float x) {
    const float ax = fabsf(x);
    const float t  = 1.0f / fmaf(0.3275911f, ax, 1.0f);
    float p = fmaf(1.061405429f, t, -1.453152027f);
    p = fmaf(p, t, 1.421413741f);
    p = fmaf(p, t, -0.284496736f);
    p = fmaf(p, t, 0.254829592f);
    p *= t;
    const float r = 1.0f - p * __expf(-ax * ax);
    return copysignf(r, x);
}
__device__ __forceinline__ float geluf(float v) {
    return 0.5f * v * (1.0f + fast_erff(v * 0.70710678118654752440f));
}

// DPP pair-sum: quad_perm{1,0,3,2} = 0xB1 adds lane^1 (validated rounds 3/4/6/7/19)
#define DPP_ADD(p, ctrl) \
    (p) += __int_as_float(__builtin_amdgcn_update_dpp(0, __float_as_int(p), (ctrl), 0xF, 0xF, true))

// ============ K_A: merged k_proj (blocks 0..511) + k_fft (blocks 512..895) ============
__global__ __launch_bounds__(256) void k_proj_fft(
    const float* __restrict__ x, const float* __restrict__ w_in,
    const float* __restrict__ conv_w, const float* __restrict__ conv_b,
    const float* __restrict__ xproj_w,
    float* __restrict__ xi_out, float* __restrict__ zs_out,
    float* __restrict__ dt_out, float* __restrict__ Bm_out,
    float* __restrict__ Cm_out, float* __restrict__ xfT)
{
    __shared__ float smem[12620];
    const int tid = threadIdx.x;

    if (blockIdx.x < 512) {
        // ---------------- proj body ----------------
        float* s_st = smem + 6476;
        const int b   = blockIdx.x >> 3;
        const int l0  = (blockIdx.x & 7) << 8;
        const int l   = l0 + tid;
        const int t   = b * L_ + l;
        const size_t t0 = (size_t)b * L_ + l0;

        float xv[DM];
        *(float4*)&xv[0] = *(const float4*)&x[t * DM + 0];
        *(float4*)&xv[4] = *(const float4*)&x[t * DM + 4];
        *(float4*)&xv[8] = *(const float4*)&x[t * DM + 8];

        float zsv[DI];
#pragma unroll
        for (int e = 0; e < DI; ++e) {
            float acc = 0.0f, accz = 0.0f;
#pragma unroll
            for (int d = 0; d < DM; ++d) {
                acc  += xv[d] * w_in[e * DM + d];
                accz += xv[d] * w_in[(DI + e) * DM + d];
            }
            smem[(tid + 3) * 25 + e] = acc;
            zsv[e] = siluf(accz);
        }
        if (tid < 3) {
            const int lh = l0 - 3 + tid;
            if (lh < 0) {
                for (int e = 0; e < DI; ++e) smem[tid * 25 + e] = 0.0f;
            } else {
                const int th = b * L_ + lh;
                float xh[DM];
                for (int d = 0; d < DM; ++d) xh[d] = x[th * DM + d];
                for (int e = 0; e < DI; ++e) {
                    float acc = 0.0f;
                    for (int d = 0; d < DM; ++d) acc += xh[d] * w_in[e * DM + d];
                    smem[tid * 25 + e] = acc;
                }
            }
        }
#pragma unroll
        for (int e = 0; e < DI; ++e) s_st[tid * DI + e] = zsv[e];
        __syncthreads();
        {
            float4* g = (float4*)(zs_out + t0 * DI);
            const float4* s4 = (const float4*)s_st;
#pragma unroll
            for (int k = 0; k < 6; ++k) g[k * 256 + tid] = s4[k * 256 + tid];
        }

        float xi[DI];
#pragma unroll
        for (int dch = 0; dch < DI; ++dch) {
            float acc = conv_b[dch];
#pragma unroll
            for (int k = 0; k < DC; ++k)
                acc += smem[(tid + k) * 25 + dch] * conv_w[dch * DC + k];
            xi[dch] = siluf(acc);
        }
        float dt = 0.0f;
#pragma unroll
        for (int d = 0; d < DI; ++d) dt += xi[d] * xproj_w[d];
        dt_out[t] = dt;
        float Bv[DS], Cv[DS];
#pragma unroll
        for (int e = 0; e < DS; ++e) {
            float accB = 0.0f, accC = 0.0f;
#pragma unroll
            for (int d = 0; d < DI; ++d) {
                accB += xi[d] * xproj_w[(1 + e) * DI + d];
                accC += xi[d] * xproj_w[(1 + DS + e) * DI + d];
            }
            Bv[e] = accB;
            Cv[e] = accC;
        }

        __syncthreads();
#pragma unroll
        for (int e = 0; e < DI; ++e) s_st[tid * DI + e] = xi[e];
        __syncthreads();
        {
            float4* g = (float4*)(xi_out + t0 * DI);
            const float4* s4 = (const float4*)s_st;
#pragma unroll
            for (int k = 0; k < 6; ++k) g[k * 256 + tid] = s4[k * 256 + tid];
        }
        __syncthreads();
#pragma unroll
        for (int e = 0; e < DS; ++e) s_st[tid * DS + e] = Bv[e];
        __syncthreads();
        {
            float4* g = (float4*)(Bm_out + t0 * DS);
            const float4* s4 = (const float4*)s_st;
#pragma unroll
            for (int k = 0; k < 4; ++k) g[k * 256 + tid] = s4[k * 256 + tid];
        }
        __syncthreads();
#pragma unroll
        for (int e = 0; e < DS; ++e) s_st[tid * DS + e] = Cv[e];
        __syncthreads();
        {
            float4* g = (float4*)(Cm_out + t0 * DS);
            const float4* s4 = (const float4*)s_st;
#pragma unroll
            for (int k = 0; k < 4; ++k) g[k * 256 + tid] = s4[k * 256 + tid];
        }
    } else {
        // ---------------- fft body ----------------
        float* re  = smem;
        float* im  = smem + 2048;
        float* twr = smem + 4096;
        float* twi = smem + 5120;
        const int bid = blockIdx.x - 512;
        const int b   = bid / (DM / 2);
        const int p   = bid % (DM / 2);
        for (int j = tid; j < 1024; j += 256) {
            const float ang = -6.283185307179586f * (float)j * (1.0f / 2048.0f);
            float s, c;
            sincosf(ang, &s, &c);
            twr[j] = c; twi[j] = s;
        }
        for (int i = tid; i < 2048; i += 256) {
            const int r = (int)(__brev((unsigned)i) >> 21);
            const float2 v = *(const float2*)&x[(size_t)(b * L_ + i) * DM + 2 * p];
            re[r] = v.x;
            im[r] = v.y;
        }
        __syncthreads();
        for (int s = 1; s <= 11; ++s) {
            const int half  = 1 << (s - 1);
            const int tstep = 2048 >> s;
            for (int i = tid; i < 1024; i += 256) {
                const int j   = i & (half - 1);
                const int grp = i >> (s - 1);
                const int pos = (grp << s) + j;
                const float wr = twr[j * tstep], wi = twi[j * tstep];
                const float ar = re[pos + half], ai = im[pos + half];
                const float vr = wr * ar - wi * ai;
                const float vi = wr * ai + wi * ar;
                const float ur = re[pos], ui = im[pos];
                re[pos] = ur + vr;          im[pos] = ui + vi;
                re[pos + half] = ur - vr;   im[pos + half] = ui - vi;
            }
            __syncthreads();
        }
        float* row1 = xfT + (size_t)(b * DM + 2 * p) * L_;
        float* row2 = row1 + L_;
        for (int k = tid; k < 2048; k += 256) {
            const int nk = (2048 - k) & 2047;
            const float zr = re[k],  zi = im[k];
            const float qr = re[nk], qi = im[nk];
            const float e1r = zr + qr, e1i = zi - qi;
            const float e2r = zr - qr, e2i = zi + qi;
            row1[k] = 0.5f * sqrtf(e1r * e1r + e1i * e1i);
            row2[k] = 0.5f * sqrtf(e2r * e2r + e2i * e2i);
        }
    }
}

// ============ S1: chunk scan — lane pair (d, q) owns 8 n-states each ============
// block = 384 = 8 chunks x 24 d x 2 q; grid = B*(NCHUNK/8) = 1024 blocks = 6144 waves
__global__ __launch_bounds__(384) void k_scan1(
    const float* __restrict__ dt_in, const float* __restrict__ xi,
    const float* __restrict__ Bm, const float* __restrict__ A_log,
    const float* __restrict__ dt_w, const float* __restrict__ dt_b,
    float* __restrict__ Sd, float* __restrict__ H)
{
    const int tid = threadIdx.x;
    const int q   = tid & 1;
    const int d   = (tid >> 1) % DI;
    const int cl  = tid / (2 * DI);       // 0..7
    const int b   = blockIdx.x >> 4;
    const int c   = ((blockIdx.x & 15) << 3) + cl;
    const int t0  = b * L_ + c * CHUNK;

    float An[8];
#pragma unroll
    for (int j = 0; j < 8; ++j) An[j] = -__expf(A_log[d * DS + q * 8 + j]);
    const float dtw = dt_w[d], dtb = dt_b[d];

    float h[8];
#pragma unroll
    for (int j = 0; j < 8; ++j) h[j] = 0.0f;
    float sumdel = 0.0f;

    const float*  pDt = dt_in + t0;
    const float*  pX  = xi + (size_t)t0 * DI + d;
    const float4* pB  = (const float4*)(Bm + (size_t)t0 * DS);

#pragma unroll 4
    for (int i = 0; i < CHUNK; ++i) {
        const float v = fmaf(pDt[i], dtw, dtb);
        const float e = __expf(v);
        const float delta = (v > 20.0f) ? v : __logf(1.0f + e);
        const float u = delta * pX[i * DI];
        sumdel += delta;
        const float4 B0 = pB[i * 4 + q * 2];
        const float4 B1 = pB[i * 4 + q * 2 + 1];
#pragma unroll
        for (int j = 0; j < 8; ++j) {
            const float a = __expf(delta * An[j]);
            h[j] = a * h[j] + u * ((j < 4) ? (&B0.x)[j] : (&B1.x)[j - 4]);
        }
    }
    const int cu = (b * DI + d) * NCHUNK + c;
    if (q == 0) Sd[cu] = sumdel;
    float4* pH = (float4*)(H + (size_t)cu * DS + q * 8);
    pH[0] = make_float4(h[0], h[1], h[2], h[3]);
    pH[1] = make_float4(h[4], h[5], h[6], h[7]);
}

// ============ S2: combine IN PLACE (H <- H0); unchanged ============
__global__ __launch_bounds__(256) void k_scan2(
    const float* __restrict__ Sd, float* __restrict__ H,
    const float* __restrict__ A_log)
{
    const int idx  = blockIdx.x * 256 + threadIdx.x;  // 24576 = (b*DI+d)*16 + n
    const int n    = idx & 15;
    const int rest = idx >> 4;                        // b*DI + d
    const int d    = rest % DI;
    const float An = -__expf(A_log[d * DS + n]);
    float Hc = 0.0f;
    const int base = rest * NCHUNK;
    for (int cg = 0; cg < NCHUNK / 8; ++cg) {
        float sd[8], hh[8];
#pragma unroll
        for (int k = 0; k < 8; ++k) {
            sd[k] = Sd[base + cg * 8 + k];
            hh[k] = H[(base + cg * 8 + k) * DS + n];
        }
        float aa[8];
#pragma unroll
        for (int k = 0; k < 8; ++k) aa[k] = __expf(An * sd[k]);
#pragma unroll
        for (int k = 0; k < 8; ++k) {
            H[(base + cg * 8 + k) * DS + n] = Hc;   // in-place: H becomes H0
            Hc = aa[k] * Hc + hh[k];
        }
    }
}

// ============ S3: replay + gate — 8 n-states/lane, DPP pair-sum for the C-dot ============
__global__ __launch_bounds__(384) void k_scan3(
    const float* __restrict__ dt_in, const float* __restrict__ xi,
    const float* __restrict__ Bm, const float* __restrict__ Cm,
    const float* __restrict__ zs, const float* __restrict__ Dp,
    const float* __restrict__ H0, const float* __restrict__ A_log,
    const float* __restrict__ dt_w, const float* __restrict__ dt_b,
    float* __restrict__ y_out)
{
    const int tid = threadIdx.x;
    const int q   = tid & 1;
    const int d   = (tid >> 1) % DI;
    const int cl  = tid / (2 * DI);       // 0..7
    const int b   = blockIdx.x >> 4;
    const int c   = ((blockIdx.x & 15) << 3) + cl;
    const int t0  = b * L_ + c * CHUNK;

    float An[8];
#pragma unroll
    for (int j = 0; j < 8; ++j) An[j] = -__expf(A_log[d * DS + q * 8 + j]);
    const float dtw = dt_w[d], dtb = dt_b[d];
    const float Dpd = Dp[d];

    const int cu = (b * DI + d) * NCHUNK + c;
    float h[8];
    {
        const float4* pH0 = (const float4*)(H0 + (size_t)cu * DS + q * 8);
        const float4 a0 = pH0[0], a1 = pH0[1];
        h[0]=a0.x; h[1]=a0.y; h[2]=a0.z; h[3]=a0.w;
        h[4]=a1.x; h[5]=a1.y; h[6]=a1.z; h[7]=a1.w;
    }

    const float*  pDt = dt_in + t0;
    const float*  pX  = xi + (size_t)t0 * DI + d;
    const float*  pZ  = zs + (size_t)t0 * DI + d;
    const float4* pB  = (const float4*)(Bm + (size_t)t0 * DS);
    const float4* pC  = (const float4*)(Cm + (size_t)t0 * DS);
    float*        pY  = y_out + (size_t)t0 * DI + d;

#pragma unroll 4
    for (int i = 0; i < CHUNK; ++i) {
        const float v = fmaf(pDt[i], dtw, dtb);
        const float e = __expf(v);
        const float delta = (v > 20.0f) ? v : __logf(1.0f + e);
        const float xiv = pX[i * DI];
        const float u = delta * xiv;
        const float4 B0 = pB[i * 4 + q * 2];
        const float4 B1 = pB[i * 4 + q * 2 + 1];
        const float4 C0 = pC[i * 4 + q * 2];
        const float4 C1 = pC[i * 4 + q * 2 + 1];
        float p = 0.0f;
#pragma unroll
        for (int j = 0; j < 8; ++j) {
            const float a = __expf(delta * An[j]);
            const float Bj = (j < 4) ? (&B0.x)[j] : (&B1.x)[j - 4];
            const float Cj = (j < 4) ? (&C0.x)[j] : (&C1.x)[j - 4];
            h[j] = a * h[j] + u * Bj;
            p += h[j] * Cj;
        }
        DPP_ADD(p, 0xB1);    // + lane^1: full 16-state sum on both lanes of the pair
        if (q == 0) pY[i * DI] = (p + xiv * Dpd) * pZ[i * DI];
    }
}

// ============ K_C: tail v6 — thread-per-token, front-loaded (unchanged) ============
__global__ __launch_bounds__(256, 2) void k_tail(
    const float* __restrict__ yg, const float* __restrict__ xfT,
    const float* __restrict__ out_w,
    const float* __restrict__ ln1_g, const float* __restrict__ ln1_b,
    const float* __restrict__ w1, const float* __restrict__ b1,
    const float* __restrict__ w2, const float* __restrict__ b2,
    const float* __restrict__ lng, const float* __restrict__ lnb,
    const float* __restrict__ cnn_w, const float* __restrict__ cnn_b,
    const float* __restrict__ l1w, const float* __restrict__ l1b,
    const float* __restrict__ l2w, const float* __restrict__ l2b,
    const float* __restrict__ l3w,
    float* __restrict__ part)
{
    __shared__ float sV[DM];
    __shared__ float sC0;
    __shared__ float sred[256];

    const int tid = threadIdx.x;
    const int b   = blockIdx.x >> 3;
    const int l   = ((blockIdx.x & 7) << 8) + tid;
    const int t   = b * L_ + l;

    float y[DI];
#pragma unroll
    for (int e = 0; e < DI; ++e) y[e] = yg[(size_t)t * DI + e];
    float xfm[DM], xf0[DM], xfp[DM];
#pragma unroll
    for (int i = 0; i < DM; ++i) {
        const float* row = xfT + (size_t)(b * DM + i) * L_;
        xfm[i] = (l == 0)      ? 0.0f : row[l - 1];
        xf0[i] = row[l];
        xfp[i] = (l == L_ - 1) ? 0.0f : row[l + 1];
    }

    if (tid < DM) {
        float acc = 0.0f;
#pragma unroll
        for (int e = 0; e < 20; ++e) acc += l3w[e] * l2w[e * DM + tid];
        sV[tid] = acc;
    }
    if (tid == DM) {
        float c = 0.0f;
#pragma unroll
        for (int e = 0; e < 20; ++e) c += l2b[e] * l3w[e];
        sC0 = c;
    }
    __syncthreads();

    float m[DM];
#pragma unroll
    for (int j = 0; j < DM; ++j) {
        float acc = 0.0f;
#pragma unroll
        for (int e = 0; e < DI; ++e) acc += y[e] * out_w[j * DI + e];
        m[j] = acc;
    }
    float mean = 0.0f;
#pragma unroll
    for (int j = 0; j < DM; ++j) mean += m[j];
    mean *= (1.0f / DM);
    float var = 0.0f;
#pragma unroll
    for (int j = 0; j < DM; ++j) { const float dv = m[j] - mean; var += dv * dv; }
    var *= (1.0f / DM);
    const float inv1 = rsqrtf(var + 1e-12f);
    float h[DM];
#pragma unroll
    for (int j = 0; j < DM; ++j) h[j] = (m[j] - mean) * inv1 * ln1_g[j] + ln1_b[j];

    float ff[4 * DM];
#pragma unroll
    for (int e = 0; e < 4 * DM; ++e) {
        float acc = b1[e];
#pragma unroll
        for (int j = 0; j < DM; ++j) acc += h[j] * w1[e * DM + j];
        ff[e] = geluf(acc);
    }
    float f2[DM];
#pragma unroll
    for (int j = 0; j < DM; ++j) {
        float acc = b2[j];
#pragma unroll
        for (int e = 0; e < 4 * DM; ++e) acc += ff[e] * w2[j * (4 * DM) + e];
        f2[j] = acc + h[j];
    }
    mean = 0.0f;
#pragma unroll
    for (int j = 0; j < DM; ++j) mean += f2[j];
    mean *= (1.0f / DM);
    var = 0.0f;
#pragma unroll
    for (int j = 0; j < DM; ++j) { const float dv = f2[j] - mean; var += dv * dv; }
    var *= (1.0f / DM);
    const float inv2 = rsqrtf(var + 1e-12f);
    float xm[DM];
#pragma unroll
    for (int j = 0; j < DM; ++j) xm[j] = (f2[j] - mean) * inv2 * lng[j] + lnb[j];

    float xc[DM];
#pragma unroll
    for (int o = 0; o < DM; ++o) {
        float acc = cnn_b[o];
#pragma unroll
        for (int i = 0; i < DM; ++i) {
            const int wb = (o * DM + i) * 3;
            acc += xfm[i] * cnn_w[wb] + xf0[i] * cnn_w[wb + 1] + xfp[i] * cnn_w[wb + 2];
        }
        xc[o] = acc;
    }

    float o3 = sC0;
#pragma unroll
    for (int d = 0; d < DM; ++d) {
        float acc = l1b[d];
#pragma unroll
        for (int e = 0; e < DM; ++e) acc += xm[e] * l1w[d * (2 * DM) + e];
#pragma unroll
        for (int e = 0; e < DM; ++e) acc += xc[e] * l1w[d * (2 * DM) + DM + e];
        o3 += eluf(acc) * sV[d];
    }

    sred[tid] = o3;
    __syncthreads();
    for (int s = 128; s > 0; s >>= 1) {
        if (tid < s) sred[tid] += sred[tid + s];
        __syncthreads();
    }
    if (tid == 0) part[blockIdx.x] = sred[0];
}

// ============ K_D: final per-batch mean + l3b + sigmoid ============
__global__ void k_final(const float* __restrict__ part, const float* __restrict__ l3b,
                        float* __restrict__ out)
{
    const int b = threadIdx.x;
    if (b < B_) {
        float s = 0.0f;
        for (int i = 0; i < 8; ++i) s += part[b * 8 + i];
        s = s * (1.0f / (float)L_) + l3b[0];
        out[b] = 1.0f / (1.0f + __expf(-s));
    }
}

extern "C" void kernel_launch(void* const* d_in, const int* in_sizes, int n_in,
                              void* d_out, int out_size, void* d_ws, size_t ws_size,
                              hipStream_t stream)
{
    const float* x        = (const float*)d_in[0];
    const float* in_w     = (const float*)d_in[1];
    const float* conv_w   = (const float*)d_in[2];
    const float* conv_b   = (const float*)d_in[3];
    const float* xproj_w  = (const float*)d_in[4];
    const float* dt_w     = (const float*)d_in[5];
    const float* dt_b     = (const float*)d_in[6];
    const float* A_log    = (const float*)d_in[7];
    const float* Dp       = (const float*)d_in[8];
    const float* out_w    = (const float*)d_in[9];
    const float* ln1_g    = (const float*)d_in[10];
    const float* ln1_b    = (const float*)d_in[11];
    const float* ffn_w1   = (const float*)d_in[12];
    const float* ffn_b1   = (const float*)d_in[13];
    const float* ffn_w2   = (const float*)d_in[14];
    const float* ffn_b2   = (const float*)d_in[15];
    const float* ffn_ln_g = (const float*)d_in[16];
    const float* ffn_ln_b = (const float*)d_in[17];
    const float* cnn_w    = (const float*)d_in[18];
    const float* cnn_b    = (const float*)d_in[19];
    const float* l1w      = (const float*)d_in[20];
    const float* l1b      = (const float*)d_in[21];
    const float* l2w      = (const float*)d_in[22];
    const float* l2b      = (const float*)d_in[23];
    const float* l3w      = (const float*)d_in[24];
    const float* l3b      = (const float*)d_in[25];
    float* out = (float*)d_out;

    float* ws = (float*)d_ws;
    const size_t nTDI = (size_t)T_ * DI;
    const size_t nTDS = (size_t)T_ * DS;
    const size_t nCH  = (size_t)B_ * DI * NCHUNK;        // 196,608
    float* w_xi   = ws;
    float* w_zs   = w_xi + nTDI;
    float* w_y    = w_zs + nTDI;
    float* w_dt   = w_y + nTDI;
    float* w_Bm   = w_dt + T_;
    float* w_Cm   = w_Bm + nTDS;
    float* w_Sd   = w_Cm + nTDS;
    float* w_H    = w_Sd + nCH;
    float* w_xf   = w_H + nCH * DS;
    float* w_part = w_xf + (size_t)B_ * DM * L_;

    k_proj_fft<<<512 + B_ * (DM / 2), 256, 0, stream>>>(
        x, in_w, conv_w, conv_b, xproj_w,
        w_xi, w_zs, w_dt, w_Bm, w_Cm, w_xf);
    k_scan1<<<B_ * (NCHUNK / 8), 384, 0, stream>>>(w_dt, w_xi, w_Bm, A_log,
                                                   dt_w, dt_b, w_Sd, w_H);
    k_scan2<<<96, 256, 0, stream>>>(w_Sd, w_H, A_log);
    k_scan3<<<B_ * (NCHUNK / 8), 384, 0, stream>>>(w_dt, w_xi, w_Bm, w_Cm, w_zs, Dp,
                                                   w_H, A_log, dt_w, dt_b, w_y);
    k_tail<<<512, 256, 0, stream>>>(w_y, w_xf, out_w,
                                    ln1_g, ln1_b, ffn_w1, ffn_b1, ffn_w2, ffn_b2,
                                    ffn_ln_g, ffn_ln_b, cnn_w, cnn_b,
                                    l1w, l1b, l2w, l2b, l3w, w_part);
    k_final<<<1, 64, 0, stream>>>(w_part, l3b, out);
}

// Round 22
// 142.787 us; speedup vs baseline: 1.0036x; 1.0023x over previous
//
#include <hip/hip_runtime.h>
#include <math.h>

#define B_  64
#define L_  2048
#define DM  12
#define DI  24
#define DS  16
#define DC  4
#define DTR 1
#define T_  (B_ * L_)        // 131072 tokens
#define NCHUNK 128
#define CHUNK  16            // L_ / NCHUNK

// ---------------- ws layout (floats) — total 18,679,808 (74.7 MB, proven) ----
// xi  : T*DI   3,145,728
// zs  : T*DI   3,145,728
// y   : T*DI   3,145,728
// dt  : T_       131,072
// Bm  : T*DS   2,097,152
// Cm  : T*DS   2,097,152
// Sd  : B*DI*NCHUNK          196,608
// H   : B*DI*NCHUNK*DS     3,145,728   (scan2 overwrites with H0 IN PLACE)
// xf  : B*DM*L             1,572,864
// part: 2048 (512 used)

__device__ __forceinline__ float siluf(float v)  { return v / (1.0f + __expf(-v)); }
__device__ __forceinline__ float eluf(float v) { return v > 0.0f ? v : __expf(v) - 1.0f; }

// Branch-free erf (Abramowitz-Stegun 7.1.26, |err| <= 1.5e-7) + gelu
__device__ __forceinline__ float fast_erff(float x) {
    const float ax = fabsf(x);
    const float t  = 1.0f / fmaf(0.3275911f, ax, 1.0f);
    float p = fmaf(1.061405429f, t, -1.453152027f);
    p = fmaf(p, t, 1.421413741f);
    p = fmaf(p, t, -0.284496736f);
    p = fmaf(p, t, 0.254829592f);
    p *= t;
    const float r = 1.0f - p * __expf(-ax * ax);
    return copysignf(r, x);
}
__device__ __forceinline__ float geluf(float v) {
    return 0.5f * v * (1.0f + fast_erff(v * 0.70710678118654752440f));
}

// DPP pair-sum: quad_perm{1,0,3,2} = 0xB1 adds lane^1 (validated rounds 3/4/6/7/19)
#define DPP_ADD(p, ctrl) \
    (p) += __int_as_float(__builtin_amdgcn_update_dpp(0, __float_as_int(p), (ctrl), 0xF, 0xF, true))

// ============ K_A: merged k_proj (blocks 0..511) + k_fft (blocks 512..895) ============
__global__ __launch_bounds__(256) void k_proj_fft(
    const float* __restrict__ x, const float* __restrict__ w_in,
    const float* __restrict__ conv_w, const float* __restrict__ conv_b,
    const float* __restrict__ xproj_w,
    float* __restrict__ xi_out, float* __restrict__ zs_out,
    float* __restrict__ dt_out, float* __restrict__ Bm_out,
    float* __restrict__ Cm_out, float* __restrict__ xfT)
{
    __shared__ float smem[12620];
    const int tid = threadIdx.x;

    if (blockIdx.x < 512) {
        // ---------------- proj body ----------------
        float* s_st = smem + 6476;
        const int b   = blockIdx.x >> 3;
        const int l0  = (blockIdx.x & 7) << 8;
        const int l   = l0 + tid;
        const int t   = b * L_ + l;
        const size_t t0 = (size_t)b * L_ + l0;

        float xv[DM];
        *(float4*)&xv[0] = *(const float4*)&x[t * DM + 0];
        *(float4*)&xv[4] = *(const float4*)&x[t * DM + 4];
        *(float4*)&xv[8] = *(const float4*)&x[t * DM + 8];

        float zsv[DI];
#pragma unroll
        for (int e = 0; e < DI; ++e) {
            float acc = 0.0f, accz = 0.0f;
#pragma unroll
            for (int d = 0; d < DM; ++d) {
                acc  += xv[d] * w_in[e * DM + d];
                accz += xv[d] * w_in[(DI + e) * DM + d];
            }
            smem[(tid + 3) * 25 + e] = acc;
            zsv[e] = siluf(accz);
        }
        if (tid < 3) {
            const int lh = l0 - 3 + tid;
            if (lh < 0) {
                for (int e = 0; e < DI; ++e) smem[tid * 25 + e] = 0.0f;
            } else {
                const int th = b * L_ + lh;
                float xh[DM];
                for (int d = 0; d < DM; ++d) xh[d] = x[th * DM + d];
                for (int e = 0; e < DI; ++e) {
                    float acc = 0.0f;
                    for (int d = 0; d < DM; ++d) acc += xh[d] * w_in[e * DM + d];
                    smem[tid * 25 + e] = acc;
                }
            }
        }
#pragma unroll
        for (int e = 0; e < DI; ++e) s_st[tid * DI + e] = zsv[e];
        __syncthreads();
        {
            float4* g = (float4*)(zs_out + t0 * DI);
            const float4* s4 = (const float4*)s_st;
#pragma unroll
            for (int k = 0; k < 6; ++k) g[k * 256 + tid] = s4[k * 256 + tid];
        }

        float xi[DI];
#pragma unroll
        for (int dch = 0; dch < DI; ++dch) {
            float acc = conv_b[dch];
#pragma unroll
            for (int k = 0; k < DC; ++k)
                acc += smem[(tid + k) * 25 + dch] * conv_w[dch * DC + k];
            xi[dch] = siluf(acc);
        }
        float dt = 0.0f;
#pragma unroll
        for (int d = 0; d < DI; ++d) dt += xi[d] * xproj_w[d];
        dt_out[t] = dt;
        float Bv[DS], Cv[DS];
#pragma unroll
        for (int e = 0; e < DS; ++e) {
            float accB = 0.0f, accC = 0.0f;
#pragma unroll
            for (int d = 0; d < DI; ++d) {
                accB += xi[d] * xproj_w[(1 + e) * DI + d];
                accC += xi[d] * xproj_w[(1 + DS + e) * DI + d];
            }
            Bv[e] = accB;
            Cv[e] = accC;
        }

        __syncthreads();
#pragma unroll
        for (int e = 0; e < DI; ++e) s_st[tid * DI + e] = xi[e];
        __syncthreads();
        {
            float4* g = (float4*)(xi_out + t0 * DI);
            const float4* s4 = (const float4*)s_st;
#pragma unroll
            for (int k = 0; k < 6; ++k) g[k * 256 + tid] = s4[k * 256 + tid];
        }
        __syncthreads();
#pragma unroll
        for (int e = 0; e < DS; ++e) s_st[tid * DS + e] = Bv[e];
        __syncthreads();
        {
            float4* g = (float4*)(Bm_out + t0 * DS);
            const float4* s4 = (const float4*)s_st;
#pragma unroll
            for (int k = 0; k < 4; ++k) g[k * 256 + tid] = s4[k * 256 + tid];
        }
        __syncthreads();
#pragma unroll
        for (int e = 0; e < DS; ++e) s_st[tid * DS + e] = Cv[e];
        __syncthreads();
        {
            float4* g = (float4*)(Cm_out + t0 * DS);
            const float4* s4 = (const float4*)s_st;
#pragma unroll
            for (int k = 0; k < 4; ++k) g[k * 256 + tid] = s4[k * 256 + tid];
        }
    } else {
        // ---------------- fft body ----------------
        float* re  = smem;
        float* im  = smem + 2048;
        float* twr = smem + 4096;
        float* twi = smem + 5120;
        const int bid = blockIdx.x - 512;
        const int b   = bid / (DM / 2);
        const int p   = bid % (DM / 2);
        for (int j = tid; j < 1024; j += 256) {
            const float ang = -6.283185307179586f * (float)j * (1.0f / 2048.0f);
            float s, c;
            sincosf(ang, &s, &c);
            twr[j] = c; twi[j] = s;
        }
        for (int i = tid; i < 2048; i += 256) {
            const int r = (int)(__brev((unsigned)i) >> 21);
            const float2 v = *(const float2*)&x[(size_t)(b * L_ + i) * DM + 2 * p];
            re[r] = v.x;
            im[r] = v.y;
        }
        __syncthreads();
        for (int s = 1; s <= 11; ++s) {
            const int half  = 1 << (s - 1);
            const int tstep = 2048 >> s;
            for (int i = tid; i < 1024; i += 256) {
                const int j   = i & (half - 1);
                const int grp = i >> (s - 1);
                const int pos = (grp << s) + j;
                const float wr = twr[j * tstep], wi = twi[j * tstep];
                const float ar = re[pos + half], ai = im[pos + half];
                const float vr = wr * ar - wi * ai;
                const float vi = wr * ai + wi * ar;
                const float ur = re[pos], ui = im[pos];
                re[pos] = ur + vr;          im[pos] = ui + vi;
                re[pos + half] = ur - vr;   im[pos + half] = ui - vi;
            }
            __syncthreads();
        }
        float* row1 = xfT + (size_t)(b * DM + 2 * p) * L_;
        float* row2 = row1 + L_;
        for (int k = tid; k < 2048; k += 256) {
            const int nk = (2048 - k) & 2047;
            const float zr = re[k],  zi = im[k];
            const float qr = re[nk], qi = im[nk];
            const float e1r = zr + qr, e1i = zi - qi;
            const float e2r = zr - qr, e2i = zi + qi;
            row1[k] = 0.5f * sqrtf(e1r * e1r + e1i * e1i);
            row2[k] = 0.5f * sqrtf(e2r * e2r + e2i * e2i);
        }
    }
}

// ============ S1: chunk scan — lane pair (d, q) owns 8 n-states each ============
// block = 384 = 8 chunks x 24 d x 2 q; grid = B*(NCHUNK/8) = 1024 blocks = 6144 waves
__global__ __launch_bounds__(384) void k_scan1(
    const float* __restrict__ dt_in, const float* __restrict__ xi,
    const float* __restrict__ Bm, const float* __restrict__ A_log,
    const float* __restrict__ dt_w, const float* __restrict__ dt_b,
    float* __restrict__ Sd, float* __restrict__ H)
{
    const int tid = threadIdx.x;
    const int q   = tid & 1;
    const int d   = (tid >> 1) % DI;
    const int cl  = tid / (2 * DI);       // 0..7
    const int b   = blockIdx.x >> 4;
    const int c   = ((blockIdx.x & 15) << 3) + cl;
    const int t0  = b * L_ + c * CHUNK;

    float An[8];
#pragma unroll
    for (int j = 0; j < 8; ++j) An[j] = -__expf(A_log[d * DS + q * 8 + j]);
    const float dtw = dt_w[d], dtb = dt_b[d];

    float h[8];
#pragma unroll
    for (int j = 0; j < 8; ++j) h[j] = 0.0f;
    float sumdel = 0.0f;

    const float*  pDt = dt_in + t0;
    const float*  pX  = xi + (size_t)t0 * DI + d;
    const float4* pB  = (const float4*)(Bm + (size_t)t0 * DS);

#pragma unroll 4
    for (int i = 0; i < CHUNK; ++i) {
        const float v = fmaf(pDt[i], dtw, dtb);
        const float e = __expf(v);
        const float delta = (v > 20.0f) ? v : __logf(1.0f + e);
        const float u = delta * pX[i * DI];
        sumdel += delta;
        const float4 B0 = pB[i * 4 + q * 2];
        const float4 B1 = pB[i * 4 + q * 2 + 1];
#pragma unroll
        for (int j = 0; j < 8; ++j) {
            const float a = __expf(delta * An[j]);
            h[j] = a * h[j] + u * ((j < 4) ? (&B0.x)[j] : (&B1.x)[j - 4]);
        }
    }
    const int cu = (b * DI + d) * NCHUNK + c;
    if (q == 0) Sd[cu] = sumdel;
    float4* pH = (float4*)(H + (size_t)cu * DS + q * 8);
    pH[0] = make_float4(h[0], h[1], h[2], h[3]);
    pH[1] = make_float4(h[4], h[5], h[6], h[7]);
}

// ============ S2: combine IN PLACE (H <- H0); unchanged ============
__global__ __launch_bounds__(256) void k_scan2(
    const float* __restrict__ Sd, float* __restrict__ H,
    const float* __restrict__ A_log)
{
    const int idx  = blockIdx.x * 256 + threadIdx.x;  // 24576 = (b*DI+d)*16 + n
    const int n    = idx & 15;
    const int rest = idx >> 4;                        // b*DI + d
    const int d    = rest % DI;
    const float An = -__expf(A_log[d * DS + n]);
    float Hc = 0.0f;
    const int base = rest * NCHUNK;
    for (int cg = 0; cg < NCHUNK / 8; ++cg) {
        float sd[8], hh[8];
#pragma unroll
        for (int k = 0; k < 8; ++k) {
            sd[k] = Sd[base + cg * 8 + k];
            hh[k] = H[(base + cg * 8 + k) * DS + n];
        }
        float aa[8];
#pragma unroll
        for (int k = 0; k < 8; ++k) aa[k] = __expf(An * sd[k]);
#pragma unroll
        for (int k = 0; k < 8; ++k) {
            H[(base + cg * 8 + k) * DS + n] = Hc;   // in-place: H becomes H0
            Hc = aa[k] * Hc + hh[k];
        }
    }
}

// ============ S3: replay + gate — 8 n-states/lane, DPP pair-sum for the C-dot ============
__global__ __launch_bounds__(384) void k_scan3(
    const float* __restrict__ dt_in, const float* __restrict__ xi,
    const float* __restrict__ Bm, const float* __restrict__ Cm,
    const float* __restrict__ zs, const float* __restrict__ Dp,
    const float* __restrict__ H0, const float* __restrict__ A_log,
    const float* __restrict__ dt_w, const float* __restrict__ dt_b,
    float* __restrict__ y_out)
{
    const int tid = threadIdx.x;
    const int q   = tid & 1;
    const int d   = (tid >> 1) % DI;
    const int cl  = tid / (2 * DI);       // 0..7
    const int b   = blockIdx.x >> 4;
    const int c   = ((blockIdx.x & 15) << 3) + cl;
    const int t0  = b * L_ + c * CHUNK;

    float An[8];
#pragma unroll
    for (int j = 0; j < 8; ++j) An[j] = -__expf(A_log[d * DS + q * 8 + j]);
    const float dtw = dt_w[d], dtb = dt_b[d];
    const float Dpd = Dp[d];

    const int cu = (b * DI + d) * NCHUNK + c;
    float h[8];
    {
        const float4* pH0 = (const float4*)(H0 + (size_t)cu * DS + q * 8);
        const float4 a0 = pH0[0], a1 = pH0[1];
        h[0]=a0.x; h[1]=a0.y; h[2]=a0.z; h[3]=a0.w;
        h[4]=a1.x; h[5]=a1.y; h[6]=a1.z; h[7]=a1.w;
    }

    const float*  pDt = dt_in + t0;
    const float*  pX  = xi + (size_t)t0 * DI + d;
    const float*  pZ  = zs + (size_t)t0 * DI + d;
    const float4* pB  = (const float4*)(Bm + (size_t)t0 * DS);
    const float4* pC  = (const float4*)(Cm + (size_t)t0 * DS);
    float*        pY  = y_out + (size_t)t0 * DI + d;

#pragma unroll 4
    for (int i = 0; i < CHUNK; ++i) {
        const float v = fmaf(pDt[i], dtw, dtb);
        const float e = __expf(v);
        const float delta = (v > 20.0f) ? v : __logf(1.0f + e);
        const float xiv = pX[i * DI];
        const float u = delta * xiv;
        const float4 B0 = pB[i * 4 + q * 2];
        const float4 B1 = pB[i * 4 + q * 2 + 1];
        const float4 C0 = pC[i * 4 + q * 2];
        const float4 C1 = pC[i * 4 + q * 2 + 1];
        float p = 0.0f;
#pragma unroll
        for (int j = 0; j < 8; ++j) {
            const float a = __expf(delta * An[j]);
            const float Bj = (j < 4) ? (&B0.x)[j] : (&B1.x)[j - 4];
            const float Cj = (j < 4) ? (&C0.x)[j] : (&C1.x)[j - 4];
            h[j] = a * h[j] + u * Bj;
            p += h[j] * Cj;
        }
        DPP_ADD(p, 0xB1);    // + lane^1: full 16-state sum on both lanes of the pair
        if (q == 0) pY[i * DI] = (p + xiv * Dpd) * pZ[i * DI];
    }
}

// ============ K_C: tail v6 — thread-per-token, front-loaded (unchanged) ============
__global__ __launch_bounds__(256, 2) void k_tail(
    const float* __restrict__ yg, const float* __restrict__ xfT,
    const float* __restrict__ out_w,
    const float* __restrict__ ln1_g, const float* __restrict__ ln1_b,
    const float* __restrict__ w1, const float* __restrict__ b1,
    const float* __restrict__ w2, const float* __restrict__ b2,
    const float* __restrict__ lng, const float* __restrict__ lnb,
    const float* __restrict__ cnn_w, const float* __restrict__ cnn_b,
    const float* __restrict__ l1w, const float* __restrict__ l1b,
    const float* __restrict__ l2w, const float* __restrict__ l2b,
    const float* __restrict__ l3w,
    float* __restrict__ part)
{
    __shared__ float sV[DM];
    __shared__ float sC0;
    __shared__ float sred[256];

    const int tid = threadIdx.x;
    const int b   = blockIdx.x >> 3;
    const int l   = ((blockIdx.x & 7) << 8) + tid;
    const int t   = b * L_ + l;

    float y[DI];
#pragma unroll
    for (int e = 0; e < DI; ++e) y[e] = yg[(size_t)t * DI + e];
    float xfm[DM], xf0[DM], xfp[DM];
#pragma unroll
    for (int i = 0; i < DM; ++i) {
        const float* row = xfT + (size_t)(b * DM + i) * L_;
        xfm[i] = (l == 0)      ? 0.0f : row[l - 1];
        xf0[i] = row[l];
        xfp[i] = (l == L_ - 1) ? 0.0f : row[l + 1];
    }

    if (tid < DM) {
        float acc = 0.0f;
#pragma unroll
        for (int e = 0; e < 20; ++e) acc += l3w[e] * l2w[e * DM + tid];
        sV[tid] = acc;
    }
    if (tid == DM) {
        float c = 0.0f;
#pragma unroll
        for (int e = 0; e < 20; ++e) c += l2b[e] * l3w[e];
        sC0 = c;
    }
    __syncthreads();

    float m[DM];
#pragma unroll
    for (int j = 0; j < DM; ++j) {
        float acc = 0.0f;
#pragma unroll
        for (int e = 0; e < DI; ++e) acc += y[e] * out_w[j * DI + e];
        m[j] = acc;
    }
    float mean = 0.0f;
#pragma unroll
    for (int j = 0; j < DM; ++j) mean += m[j];
    mean *= (1.0f / DM);
    float var = 0.0f;
#pragma unroll
    for (int j = 0; j < DM; ++j) { const float dv = m[j] - mean; var += dv * dv; }
    var *= (1.0f / DM);
    const float inv1 = rsqrtf(var + 1e-12f);
    float h[DM];
#pragma unroll
    for (int j = 0; j < DM; ++j) h[j] = (m[j] - mean) * inv1 * ln1_g[j] + ln1_b[j];

    float ff[4 * DM];
#pragma unroll
    for (int e = 0; e < 4 * DM; ++e) {
        float acc = b1[e];
#pragma unroll
        for (int j = 0; j < DM; ++j) acc += h[j] * w1[e * DM + j];
        ff[e] = geluf(acc);
    }
    float f2[DM];
#pragma unroll
    for (int j = 0; j < DM; ++j) {
        float acc = b2[j];
#pragma unroll
        for (int e = 0; e < 4 * DM; ++e) acc += ff[e] * w2[j * (4 * DM) + e];
        f2[j] = acc + h[j];
    }
    mean = 0.0f;
#pragma unroll
    for (int j = 0; j < DM; ++j) mean += f2[j];
    mean *= (1.0f / DM);
    var = 0.0f;
#pragma unroll
    for (int j = 0; j < DM; ++j) { const float dv = f2[j] - mean; var += dv * dv; }
    var *= (1.0f / DM);
    const float inv2 = rsqrtf(var + 1e-12f);
    float xm[DM];
#pragma unroll
    for (int j = 0; j < DM; ++j) xm[j] = (f2[j] - mean) * inv2 * lng[j] + lnb[j];

    float xc[DM];
#pragma unroll
    for (int o = 0; o < DM; ++o) {
        float acc = cnn_b[o];
#pragma unroll
        for (int i = 0; i < DM; ++i) {
            const int wb = (o * DM + i) * 3;
            acc += xfm[i] * cnn_w[wb] + xf0[i] * cnn_w[wb + 1] + xfp[i] * cnn_w[wb + 2];
        }
        xc[o] = acc;
    }

    float o3 = sC0;
#pragma unroll
    for (int d = 0; d < DM; ++d) {
        float acc = l1b[d];
#pragma unroll
        for (int e = 0; e < DM; ++e) acc += xm[e] * l1w[d * (2 * DM) + e];
#pragma unroll
        for (int e = 0; e < DM; ++e) acc += xc[e] * l1w[d * (2 * DM) + DM + e];
        o3 += eluf(acc) * sV[d];
    }

    sred[tid] = o3;
    __syncthreads();
    for (int s = 128; s > 0; s >>= 1) {
        if (tid < s) sred[tid] += sred[tid + s];
        __syncthreads();
    }
    if (tid == 0) part[blockIdx.x] = sred[0];
}

// ============ K_D: final per-batch mean + l3b + sigmoid ============
__global__ void k_final(const float* __restrict__ part, const float* __restrict__ l3b,
                        float* __restrict__ out)
{
    const int b = threadIdx.x;
    if (b < B_) {
        float s = 0.0f;
        for (int i = 0; i < 8; ++i) s += part[b * 8 + i];
        s = s * (1.0f / (float)L_) + l3b[0];
        out[b] = 1.0f / (1.0f + __expf(-s));
    }
}

extern "C" void kernel_launch(void* const* d_in, const int* in_sizes, int n_in,
                              void* d_out, int out_size, void* d_ws, size_t ws_size,
                              hipStream_t stream)
{
    const float* x        = (const float*)d_in[0];
    const float* in_w     = (const float*)d_in[1];
    const float* conv_w   = (const float*)d_in[2];
    const float* conv_b   = (const float*)d_in[3];
    const float* xproj_w  = (const float*)d_in[4];
    const float* dt_w     = (const float*)d_in[5];
    const float* dt_b     = (const float*)d_in[6];
    const float* A_log    = (const float*)d_in[7];
    const float* Dp       = (const float*)d_in[8];
    const float* out_w    = (const float*)d_in[9];
    const float* ln1_g    = (const float*)d_in[10];
    const float* ln1_b    = (const float*)d_in[11];
    const float* ffn_w1   = (const float*)d_in[12];
    const float* ffn_b1   = (const float*)d_in[13];
    const float* ffn_w2   = (const float*)d_in[14];
    const float* ffn_b2   = (const float*)d_in[15];
    const float* ffn_ln_g = (const float*)d_in[16];
    const float* ffn_ln_b = (const float*)d_in[17];
    const float* cnn_w    = (const float*)d_in[18];
    const float* cnn_b    = (const float*)d_in[19];
    const float* l1w      = (const float*)d_in[20];
    const float* l1b      = (const float*)d_in[21];
    const float* l2w      = (const float*)d_in[22];
    const float* l2b      = (const float*)d_in[23];
    const float* l3w      = (const float*)d_in[24];
    const float* l3b      = (const float*)d_in[25];
    float* out = (float*)d_out;

    float* ws = (float*)d_ws;
    const size_t nTDI = (size_t)T_ * DI;
    const size_t nTDS = (size_t)T_ * DS;
    const size_t nCH  = (size_t)B_ * DI * NCHUNK;        // 196,608
    float* w_xi   = ws;
    float* w_zs   = w_xi + nTDI;
    float* w_y    = w_zs + nTDI;
    float* w_dt   = w_y + nTDI;
    float* w_Bm   = w_dt + T_;
    float* w_Cm   = w_Bm + nTDS;
    float* w_Sd   = w_Cm + nTDS;
    float* w_H    = w_Sd + nCH;
    float* w_xf   = w_H + nCH * DS;
    float* w_part = w_xf + (size_t)B_ * DM * L_;

    k_proj_fft<<<512 + B_ * (DM / 2), 256, 0, stream>>>(
        x, in_w, conv_w, conv_b, xproj_w,
        w_xi, w_zs, w_dt, w_Bm, w_Cm, w_xf);
    k_scan1<<<B_ * (NCHUNK / 8), 384, 0, stream>>>(w_dt, w_xi, w_Bm, A_log,
                                                   dt_w, dt_b, w_Sd, w_H);
    k_scan2<<<96, 256, 0, stream>>>(w_Sd, w_H, A_log);
    k_scan3<<<B_ * (NCHUNK / 8), 384, 0, stream>>>(w_dt, w_xi, w_Bm, w_Cm, w_zs, Dp,
                                                   w_H, A_log, dt_w, dt_b, w_y);
    k_tail<<<512, 256, 0, stream>>>(w_y, w_xf, out_w,
                                    ln1_g, ln1_b, ffn_w1, ffn_b1, ffn_w2, ffn_b2,
                                    ffn_ln_g, ffn_ln_b, cnn_w, cnn_b,
                                    l1w, l1b, l2w, l2b, l3w, w_part);
    k_final<<<1, 64, 0, stream>>>(w_part, l3b, out);
}

// Round 23
// 141.781 us; speedup vs baseline: 1.0107x; 1.0071x over previous
//
#include <hip/hip_runtime.h>
#include <math.h>

#define B_  64
#define L_  2048
#define DM  12
#define DI  24
#define DS  16
#define DC  4
#define DTR 1
#define T_  (B_ * L_)        // 131072 tokens
#define NCHUNK 128
#define CHUNK  16            // L_ / NCHUNK

// ---------------- ws layout (floats) — total 18,679,808 (74.7 MB, proven) ----
// xi  : T*DI   3,145,728
// zs  : T*DI   3,145,728
// y   : T*DI   3,145,728
// dt  : T_       131,072
// Bm  : T*DS   2,097,152
// Cm  : T*DS   2,097,152
// Sd  : B*DI*NCHUNK          196,608
// H   : B*DI*NCHUNK*DS     3,145,728   (scan2 overwrites with H0 IN PLACE)
// xf  : B*DM*L             1,572,864
// part: 2048 (512 used)

__device__ __forceinline__ float siluf(float v)  { return v / (1.0f + __expf(-v)); }
__device__ __forceinline__ float eluf(float v) { return v > 0.0f ? v : __expf(v) - 1.0f; }

// Branch-free erf (Abramowitz-Stegun 7.1.26, |err| <= 1.5e-7) + gelu
__device__ __forceinline__ float fast_erff(float x) {
    const float ax = fabsf(x);
    const float t  = 1.0f / fmaf(0.3275911f, ax, 1.0f);
    float p = fmaf(1.061405429f, t, -1.453152027f);
    p = fmaf(p, t, 1.421413741f);
    p = fmaf(p, t, -0.284496736f);
    p = fmaf(p, t, 0.254829592f);
    p *= t;
    const float r = 1.0f - p * __expf(-ax * ax);
    return copysignf(r, x);
}
__device__ __forceinline__ float geluf(float v) {
    return 0.5f * v * (1.0f + fast_erff(v * 0.70710678118654752440f));
}

// DPP pair-sum: quad_perm{1,0,3,2} = 0xB1 adds lane^1 (validated rounds 3/4/6/7/19)
#define DPP_ADD(p, ctrl) \
    (p) += __int_as_float(__builtin_amdgcn_update_dpp(0, __float_as_int(p), (ctrl), 0xF, 0xF, true))

// ============ K_A: merged k_proj (blocks 0..511) + k_fft (blocks 512..895) ============
__global__ __launch_bounds__(256) void k_proj_fft(
    const float* __restrict__ x, const float* __restrict__ w_in,
    const float* __restrict__ conv_w, const float* __restrict__ conv_b,
    const float* __restrict__ xproj_w,
    float* __restrict__ xi_out, float* __restrict__ zs_out,
    float* __restrict__ dt_out, float* __restrict__ Bm_out,
    float* __restrict__ Cm_out, float* __restrict__ xfT)
{
    __shared__ float smem[12620];
    const int tid = threadIdx.x;

    if (blockIdx.x < 512) {
        // ---------------- proj body ----------------
        float* s_st = smem + 6476;
        const int b   = blockIdx.x >> 3;
        const int l0  = (blockIdx.x & 7) << 8;
        const int l   = l0 + tid;
        const int t   = b * L_ + l;
        const size_t t0 = (size_t)b * L_ + l0;

        float xv[DM];
        *(float4*)&xv[0] = *(const float4*)&x[t * DM + 0];
        *(float4*)&xv[4] = *(const float4*)&x[t * DM + 4];
        *(float4*)&xv[8] = *(const float4*)&x[t * DM + 8];

        float zsv[DI];
#pragma unroll
        for (int e = 0; e < DI; ++e) {
            float acc = 0.0f, accz = 0.0f;
#pragma unroll
            for (int d = 0; d < DM; ++d) {
                acc  += xv[d] * w_in[e * DM + d];
                accz += xv[d] * w_in[(DI + e) * DM + d];
            }
            smem[(tid + 3) * 25 + e] = acc;
            zsv[e] = siluf(accz);
        }
        if (tid < 3) {
            const int lh = l0 - 3 + tid;
            if (lh < 0) {
                for (int e = 0; e < DI; ++e) smem[tid * 25 + e] = 0.0f;
            } else {
                const int th = b * L_ + lh;
                float xh[DM];
                for (int d = 0; d < DM; ++d) xh[d] = x[th * DM + d];
                for (int e = 0; e < DI; ++e) {
                    float acc = 0.0f;
                    for (int d = 0; d < DM; ++d) acc += xh[d] * w_in[e * DM + d];
                    smem[tid * 25 + e] = acc;
                }
            }
        }
#pragma unroll
        for (int e = 0; e < DI; ++e) s_st[tid * DI + e] = zsv[e];
        __syncthreads();
        {
            float4* g = (float4*)(zs_out + t0 * DI);
            const float4* s4 = (const float4*)s_st;
#pragma unroll
            for (int k = 0; k < 6; ++k) g[k * 256 + tid] = s4[k * 256 + tid];
        }

        float xi[DI];
#pragma unroll
        for (int dch = 0; dch < DI; ++dch) {
            float acc = conv_b[dch];
#pragma unroll
            for (int k = 0; k < DC; ++k)
                acc += smem[(tid + k) * 25 + dch] * conv_w[dch * DC + k];
            xi[dch] = siluf(acc);
        }
        float dt = 0.0f;
#pragma unroll
        for (int d = 0; d < DI; ++d) dt += xi[d] * xproj_w[d];
        dt_out[t] = dt;
        float Bv[DS], Cv[DS];
#pragma unroll
        for (int e = 0; e < DS; ++e) {
            float accB = 0.0f, accC = 0.0f;
#pragma unroll
            for (int d = 0; d < DI; ++d) {
                accB += xi[d] * xproj_w[(1 + e) * DI + d];
                accC += xi[d] * xproj_w[(1 + DS + e) * DI + d];
            }
            Bv[e] = accB;
            Cv[e] = accC;
        }

        __syncthreads();
#pragma unroll
        for (int e = 0; e < DI; ++e) s_st[tid * DI + e] = xi[e];
        __syncthreads();
        {
            float4* g = (float4*)(xi_out + t0 * DI);
            const float4* s4 = (const float4*)s_st;
#pragma unroll
            for (int k = 0; k < 6; ++k) g[k * 256 + tid] = s4[k * 256 + tid];
        }
        __syncthreads();
#pragma unroll
        for (int e = 0; e < DS; ++e) s_st[tid * DS + e] = Bv[e];
        __syncthreads();
        {
            float4* g = (float4*)(Bm_out + t0 * DS);
            const float4* s4 = (const float4*)s_st;
#pragma unroll
            for (int k = 0; k < 4; ++k) g[k * 256 + tid] = s4[k * 256 + tid];
        }
        __syncthreads();
#pragma unroll
        for (int e = 0; e < DS; ++e) s_st[tid * DS + e] = Cv[e];
        __syncthreads();
        {
            float4* g = (float4*)(Cm_out + t0 * DS);
            const float4* s4 = (const float4*)s_st;
#pragma unroll
            for (int k = 0; k < 4; ++k) g[k * 256 + tid] = s4[k * 256 + tid];
        }
    } else {
        // ---------------- fft body ----------------
        float* re  = smem;
        float* im  = smem + 2048;
        float* twr = smem + 4096;
        float* twi = smem + 5120;
        const int bid = blockIdx.x - 512;
        const int b   = bid / (DM / 2);
        const int p   = bid % (DM / 2);
        for (int j = tid; j < 1024; j += 256) {
            const float ang = -6.283185307179586f * (float)j * (1.0f / 2048.0f);
            float s, c;
            sincosf(ang, &s, &c);
            twr[j] = c; twi[j] = s;
        }
        for (int i = tid; i < 2048; i += 256) {
            const int r = (int)(__brev((unsigned)i) >> 21);
            const float2 v = *(const float2*)&x[(size_t)(b * L_ + i) * DM + 2 * p];
            re[r] = v.x;
            im[r] = v.y;
        }
        __syncthreads();
        for (int s = 1; s <= 11; ++s) {
            const int half  = 1 << (s - 1);
            const int tstep = 2048 >> s;
            for (int i = tid; i < 1024; i += 256) {
                const int j   = i & (half - 1);
                const int grp = i >> (s - 1);
                const int pos = (grp << s) + j;
                const float wr = twr[j * tstep], wi = twi[j * tstep];
                const float ar = re[pos + half], ai = im[pos + half];
                const float vr = wr * ar - wi * ai;
                const float vi = wr * ai + wi * ar;
                const float ur = re[pos], ui = im[pos];
                re[pos] = ur + vr;          im[pos] = ui + vi;
                re[pos + half] = ur - vr;   im[pos + half] = ui - vi;
            }
            __syncthreads();
        }
        float* row1 = xfT + (size_t)(b * DM + 2 * p) * L_;
        float* row2 = row1 + L_;
        for (int k = tid; k < 2048; k += 256) {
            const int nk = (2048 - k) & 2047;
            const float zr = re[k],  zi = im[k];
            const float qr = re[nk], qi = im[nk];
            const float e1r = zr + qr, e1i = zi - qi;
            const float e2r = zr - qr, e2i = zi + qi;
            row1[k] = 0.5f * sqrtf(e1r * e1r + e1i * e1i);
            row2[k] = 0.5f * sqrtf(e2r * e2r + e2i * e2i);
        }
    }
}

// ============ S1: chunk scan — lane pair (d, q) owns 8 n-states each ============
// block = 384 = 8 chunks x 24 d x 2 q; grid = B*(NCHUNK/8) = 1024 blocks = 6144 waves
__global__ __launch_bounds__(384) void k_scan1(
    const float* __restrict__ dt_in, const float* __restrict__ xi,
    const float* __restrict__ Bm, const float* __restrict__ A_log,
    const float* __restrict__ dt_w, const float* __restrict__ dt_b,
    float* __restrict__ Sd, float* __restrict__ H)
{
    const int tid = threadIdx.x;
    const int q   = tid & 1;
    const int d   = (tid >> 1) % DI;
    const int cl  = tid / (2 * DI);       // 0..7
    const int b   = blockIdx.x >> 4;
    const int c   = ((blockIdx.x & 15) << 3) + cl;
    const int t0  = b * L_ + c * CHUNK;

    float An[8];
#pragma unroll
    for (int j = 0; j < 8; ++j) An[j] = -__expf(A_log[d * DS + q * 8 + j]);
    const float dtw = dt_w[d], dtb = dt_b[d];

    float h[8];
#pragma unroll
    for (int j = 0; j < 8; ++j) h[j] = 0.0f;
    float sumdel = 0.0f;

    const float*  pDt = dt_in + t0;
    const float*  pX  = xi + (size_t)t0 * DI + d;
    const float4* pB  = (const float4*)(Bm + (size_t)t0 * DS);

#pragma unroll 4
    for (int i = 0; i < CHUNK; ++i) {
        const float v = fmaf(pDt[i], dtw, dtb);
        const float e = __expf(v);
        const float delta = (v > 20.0f) ? v : __logf(1.0f + e);
        const float u = delta * pX[i * DI];
        sumdel += delta;
        const float4 B0 = pB[i * 4 + q * 2];
        const float4 B1 = pB[i * 4 + q * 2 + 1];
#pragma unroll
        for (int j = 0; j < 8; ++j) {
            const float a = __expf(delta * An[j]);
            h[j] = a * h[j] + u * ((j < 4) ? (&B0.x)[j] : (&B1.x)[j - 4]);
        }
    }
    const int cu = (b * DI + d) * NCHUNK + c;
    if (q == 0) Sd[cu] = sumdel;
    float4* pH = (float4*)(H + (size_t)cu * DS + q * 8);
    pH[0] = make_float4(h[0], h[1], h[2], h[3]);
    pH[1] = make_float4(h[4], h[5], h[6], h[7]);
}

// ============ S2: combine IN PLACE (H <- H0); unchanged ============
__global__ __launch_bounds__(256) void k_scan2(
    const float* __restrict__ Sd, float* __restrict__ H,
    const float* __restrict__ A_log)
{
    const int idx  = blockIdx.x * 256 + threadIdx.x;  // 24576 = (b*DI+d)*16 + n
    const int n    = idx & 15;
    const int rest = idx >> 4;                        // b*DI + d
    const int d    = rest % DI;
    const float An = -__expf(A_log[d * DS + n]);
    float Hc = 0.0f;
    const int base = rest * NCHUNK;
    for (int cg = 0; cg < NCHUNK / 8; ++cg) {
        float sd[8], hh[8];
#pragma unroll
        for (int k = 0; k < 8; ++k) {
            sd[k] = Sd[base + cg * 8 + k];
            hh[k] = H[(base + cg * 8 + k) * DS + n];
        }
        float aa[8];
#pragma unroll
        for (int k = 0; k < 8; ++k) aa[k] = __expf(An * sd[k]);
#pragma unroll
        for (int k = 0; k < 8; ++k) {
            H[(base + cg * 8 + k) * DS + n] = Hc;   // in-place: H becomes H0
            Hc = aa[k] * Hc + hh[k];
        }
    }
}

// ============ S3: replay + gate — 8 n-states/lane, DPP pair-sum for the C-dot ============
__global__ __launch_bounds__(384) void k_scan3(
    const float* __restrict__ dt_in, const float* __restrict__ xi,
    const float* __restrict__ Bm, const float* __restrict__ Cm,
    const float* __restrict__ zs, const float* __restrict__ Dp,
    const float* __restrict__ H0, const float* __restrict__ A_log,
    const float* __restrict__ dt_w, const float* __restrict__ dt_b,
    float* __restrict__ y_out)
{
    const int tid = threadIdx.x;
    const int q   = tid & 1;
    const int d   = (tid >> 1) % DI;
    const int cl  = tid / (2 * DI);       // 0..7
    const int b   = blockIdx.x >> 4;
    const int c   = ((blockIdx.x & 15) << 3) + cl;
    const int t0  = b * L_ + c * CHUNK;

    float An[8];
#pragma unroll
    for (int j = 0; j < 8; ++j) An[j] = -__expf(A_log[d * DS + q * 8 + j]);
    const float dtw = dt_w[d], dtb = dt_b[d];
    const float Dpd = Dp[d];

    const int cu = (b * DI + d) * NCHUNK + c;
    float h[8];
    {
        const float4* pH0 = (const float4*)(H0 + (size_t)cu * DS + q * 8);
        const float4 a0 = pH0[0], a1 = pH0[1];
        h[0]=a0.x; h[1]=a0.y; h[2]=a0.z; h[3]=a0.w;
        h[4]=a1.x; h[5]=a1.y; h[6]=a1.z; h[7]=a1.w;
    }

    const float*  pDt = dt_in + t0;
    const float*  pX  = xi + (size_t)t0 * DI + d;
    const float*  pZ  = zs + (size_t)t0 * DI + d;
    const float4* pB  = (const float4*)(Bm + (size_t)t0 * DS);
    const float4* pC  = (const float4*)(Cm + (size_t)t0 * DS);
    float*        pY  = y_out + (size_t)t0 * DI + d;

#pragma unroll 4
    for (int i = 0; i < CHUNK; ++i) {
        const float v = fmaf(pDt[i], dtw, dtb);
        const float e = __expf(v);
        const float delta = (v > 20.0f) ? v : __logf(1.0f + e);
        const float xiv = pX[i * DI];
        const float u = delta * xiv;
        const float4 B0 = pB[i * 4 + q * 2];
        const float4 B1 = pB[i * 4 + q * 2 + 1];
        const float4 C0 = pC[i * 4 + q * 2];
        const float4 C1 = pC[i * 4 + q * 2 + 1];
        float p = 0.0f;
#pragma unroll
        for (int j = 0; j < 8; ++j) {
            const float a = __expf(delta * An[j]);
            const float Bj = (j < 4) ? (&B0.x)[j] : (&B1.x)[j - 4];
            const float Cj = (j < 4) ? (&C0.x)[j] : (&C1.x)[j - 4];
            h[j] = a * h[j] + u * Bj;
            p += h[j] * Cj;
        }
        DPP_ADD(p, 0xB1);    // + lane^1: full 16-state sum on both lanes of the pair
        if (q == 0) pY[i * DI] = (p + xiv * Dpd) * pZ[i * DI];
    }
}

// ============ K_C: tail v6 — thread-per-token, front-loaded (unchanged) ============
__global__ __launch_bounds__(256, 2) void k_tail(
    const float* __restrict__ yg, const float* __restrict__ xfT,
    const float* __restrict__ out_w,
    const float* __restrict__ ln1_g, const float* __restrict__ ln1_b,
    const float* __restrict__ w1, const float* __restrict__ b1,
    const float* __restrict__ w2, const float* __restrict__ b2,
    const float* __restrict__ lng, const float* __restrict__ lnb,
    const float* __restrict__ cnn_w, const float* __restrict__ cnn_b,
    const float* __restrict__ l1w, const float* __restrict__ l1b,
    const float* __restrict__ l2w, const float* __restrict__ l2b,
    const float* __restrict__ l3w,
    float* __restrict__ part)
{
    __shared__ float sV[DM];
    __shared__ float sC0;
    __shared__ float sred[256];

    const int tid = threadIdx.x;
    const int b   = blockIdx.x >> 3;
    const int l   = ((blockIdx.x & 7) << 8) + tid;
    const int t   = b * L_ + l;

    float y[DI];
#pragma unroll
    for (int e = 0; e < DI; ++e) y[e] = yg[(size_t)t * DI + e];
    float xfm[DM], xf0[DM], xfp[DM];
#pragma unroll
    for (int i = 0; i < DM; ++i) {
        const float* row = xfT + (size_t)(b * DM + i) * L_;
        xfm[i] = (l == 0)      ? 0.0f : row[l - 1];
        xf0[i] = row[l];
        xfp[i] = (l == L_ - 1) ? 0.0f : row[l + 1];
    }

    if (tid < DM) {
        float acc = 0.0f;
#pragma unroll
        for (int e = 0; e < 20; ++e) acc += l3w[e] * l2w[e * DM + tid];
        sV[tid] = acc;
    }
    if (tid == DM) {
        float c = 0.0f;
#pragma unroll
        for (int e = 0; e < 20; ++e) c += l2b[e] * l3w[e];
        sC0 = c;
    }
    __syncthreads();

    float m[DM];
#pragma unroll
    for (int j = 0; j < DM; ++j) {
        float acc = 0.0f;
#pragma unroll
        for (int e = 0; e < DI; ++e) acc += y[e] * out_w[j * DI + e];
        m[j] = acc;
    }
    float mean = 0.0f;
#pragma unroll
    for (int j = 0; j < DM; ++j) mean += m[j];
    mean *= (1.0f / DM);
    float var = 0.0f;
#pragma unroll
    for (int j = 0; j < DM; ++j) { const float dv = m[j] - mean; var += dv * dv; }
    var *= (1.0f / DM);
    const float inv1 = rsqrtf(var + 1e-12f);
    float h[DM];
#pragma unroll
    for (int j = 0; j < DM; ++j) h[j] = (m[j] - mean) * inv1 * ln1_g[j] + ln1_b[j];

    float ff[4 * DM];
#pragma unroll
    for (int e = 0; e < 4 * DM; ++e) {
        float acc = b1[e];
#pragma unroll
        for (int j = 0; j < DM; ++j) acc += h[j] * w1[e * DM + j];
        ff[e] = geluf(acc);
    }
    float f2[DM];
#pragma unroll
    for (int j = 0; j < DM; ++j) {
        float acc = b2[j];
#pragma unroll
        for (int e = 0; e < 4 * DM; ++e) acc += ff[e] * w2[j * (4 * DM) + e];
        f2[j] = acc + h[j];
    }
    mean = 0.0f;
#pragma unroll
    for (int j = 0; j < DM; ++j) mean += f2[j];
    mean *= (1.0f / DM);
    var = 0.0f;
#pragma unroll
    for (int j = 0; j < DM; ++j) { const float dv = f2[j] - mean; var += dv * dv; }
    var *= (1.0f / DM);
    const float inv2 = rsqrtf(var + 1e-12f);
    float xm[DM];
#pragma unroll
    for (int j = 0; j < DM; ++j) xm[j] = (f2[j] - mean) * inv2 * lng[j] + lnb[j];

    float xc[DM];
#pragma unroll
    for (int o = 0; o < DM; ++o) {
        float acc = cnn_b[o];
#pragma unroll
        for (int i = 0; i < DM; ++i) {
            const int wb = (o * DM + i) * 3;
            acc += xfm[i] * cnn_w[wb] + xf0[i] * cnn_w[wb + 1] + xfp[i] * cnn_w[wb + 2];
        }
        xc[o] = acc;
    }

    float o3 = sC0;
#pragma unroll
    for (int d = 0; d < DM; ++d) {
        float acc = l1b[d];
#pragma unroll
        for (int e = 0; e < DM; ++e) acc += xm[e] * l1w[d * (2 * DM) + e];
#pragma unroll
        for (int e = 0; e < DM; ++e) acc += xc[e] * l1w[d * (2 * DM) + DM + e];
        o3 += eluf(acc) * sV[d];
    }

    sred[tid] = o3;
    __syncthreads();
    for (int s = 128; s > 0; s >>= 1) {
        if (tid < s) sred[tid] += sred[tid + s];
        __syncthreads();
    }
    if (tid == 0) part[blockIdx.x] = sred[0];
}

// ============ K_D: final per-batch mean + l3b + sigmoid ============
__global__ void k_final(const float* __restrict__ part, const float* __restrict__ l3b,
                        float* __restrict__ out)
{
    const int b = threadIdx.x;
    if (b < B_) {
        float s = 0.0f;
        for (int i = 0; i < 8; ++i) s += part[b * 8 + i];
        s = s * (1.0f / (float)L_) + l3b[0];
        out[b] = 1.0f / (1.0f + __expf(-s));
    }
}

extern "C" void kernel_launch(void* const* d_in, const int* in_sizes, int n_in,
                              void* d_out, int out_size, void* d_ws, size_t ws_size,
                              hipStream_t stream)
{
    const float* x        = (const float*)d_in[0];
    const float* in_w     = (const float*)d_in[1];
    const float* conv_w   = (const float*)d_in[2];
    const float* conv_b   = (const float*)d_in[3];
    const float* xproj_w  = (const float*)d_in[4];
    const float* dt_w     = (const float*)d_in[5];
    const float* dt_b     = (const float*)d_in[6];
    const float* A_log    = (const float*)d_in[7];
    const float* Dp       = (const float*)d_in[8];
    const float* out_w    = (const float*)d_in[9];
    const float* ln1_g    = (const float*)d_in[10];
    const float* ln1_b    = (const float*)d_in[11];
    const float* ffn_w1   = (const float*)d_in[12];
    const float* ffn_b1   = (const float*)d_in[13];
    const float* ffn_w2   = (const float*)d_in[14];
    const float* ffn_b2   = (const float*)d_in[15];
    const float* ffn_ln_g = (const float*)d_in[16];
    const float* ffn_ln_b = (const float*)d_in[17];
    const float* cnn_w    = (const float*)d_in[18];
    const float* cnn_b    = (const float*)d_in[19];
    const float* l1w      = (const float*)d_in[20];
    const float* l1b      = (const float*)d_in[21];
    const float* l2w      = (const float*)d_in[22];
    const float* l2b      = (const float*)d_in[23];
    const float* l3w      = (const float*)d_in[24];
    const float* l3b      = (const float*)d_in[25];
    float* out = (float*)d_out;

    float* ws = (float*)d_ws;
    const size_t nTDI = (size_t)T_ * DI;
    const size_t nTDS = (size_t)T_ * DS;
    const size_t nCH  = (size_t)B_ * DI * NCHUNK;        // 196,608
    float* w_xi   = ws;
    float* w_zs   = w_xi + nTDI;
    float* w_y    = w_zs + nTDI;
    float* w_dt   = w_y + nTDI;
    float* w_Bm   = w_dt + T_;
    float* w_Cm   = w_Bm + nTDS;
    float* w_Sd   = w_Cm + nTDS;
    float* w_H    = w_Sd + nCH;
    float* w_xf   = w_H + nCH * DS;
    float* w_part = w_xf + (size_t)B_ * DM * L_;

    k_proj_fft<<<512 + B_ * (DM / 2), 256, 0, stream>>>(
        x, in_w, conv_w, conv_b, xproj_w,
        w_xi, w_zs, w_dt, w_Bm, w_Cm, w_xf);
    k_scan1<<<B_ * (NCHUNK / 8), 384, 0, stream>>>(w_dt, w_xi, w_Bm, A_log,
                                                   dt_w, dt_b, w_Sd, w_H);
    k_scan2<<<96, 256, 0, stream>>>(w_Sd, w_H, A_log);
    k_scan3<<<B_ * (NCHUNK / 8), 384, 0, stream>>>(w_dt, w_xi, w_Bm, w_Cm, w_zs, Dp,
                                                   w_H, A_log, dt_w, dt_b, w_y);
    k_tail<<<512, 256, 0, stream>>>(w_y, w_xf, out_w,
                                    ln1_g, ln1_b, ffn_w1, ffn_b1, ffn_w2, ffn_b2,
                                    ffn_ln_g, ffn_ln_b, cnn_w, cnn_b,
                                    l1w, l1b, l2w, l2b, l3w, w_part);
    k_final<<<1, 64, 0, stream>>>(w_part, l3b, out);
}